// Round 8
// baseline (3439.849 us; speedup 1.0000x reference)
//
#include <hip/hip_runtime.h>
#include <hip/hip_bf16.h>

#define B_ 64
#define T_ 512
#define D_ 512
#define K_ 256
#define G3 1536   // 3*D

typedef __attribute__((ext_vector_type(8))) short sh8;   // 8 x bf16 bits (4 VGPR)
typedef __attribute__((ext_vector_type(4))) short sh4;
typedef __attribute__((ext_vector_type(4))) float fx4;
typedef __attribute__((ext_vector_type(4))) int   ix4;

__device__ __forceinline__ short f2bf(float x) {
  __hip_bfloat16 h = __float2bfloat16(x);
  union { __hip_bfloat16 h; short s; } u; u.h = h; return u.s;
}
__device__ __forceinline__ float sigm(float x) { return 1.f / (1.f + __expf(-x)); }
__device__ __forceinline__ float tanh_fast(float x) {
  float e2 = __expf(-2.f * x);
  return (1.f - e2) / (1.f + e2);
}

// ---------------- codebook squared norms (f64) ----------------
__global__ void k_cnorm(const float* __restrict__ cb, double* __restrict__ cn) {
  int c = threadIdx.x;
  if (c < K_) {
    double s = 0.0;
    for (int k = 0; k < D_; ++k) { double v = cb[c * D_ + k]; s += v * v; }
    cn[c] = s;
  }
}

// ---- code_gates = codebook @ w_ih.T + b_ih (+ b_hh folded for r,z gates) ----
__global__ __launch_bounds__(256) void k_cg(const float* __restrict__ cb,
                                            const float* __restrict__ wih,
                                            const float* __restrict__ bih,
                                            const float* __restrict__ bhh,
                                            float* __restrict__ cg) {
  __shared__ float wl[16][512];
  int j0 = blockIdx.x * 16, c0 = blockIdx.y * 64;
  for (int v = threadIdx.x; v < 16 * 128; v += 256) {
    int r = v >> 7, q = v & 127;
    *(fx4*)&wl[r][q * 4] = *(const fx4*)&wih[(j0 + r) * D_ + q * 4];
  }
  __syncthreads();
  for (int p = threadIdx.x; p < 1024; p += 256) {
    int j = p >> 6, c = c0 + (p & 63);
    fx4 a = {0.f, 0.f, 0.f, 0.f};
    const float* cbr = &cb[c * D_];
    for (int q = 0; q < 128; ++q) {
      fx4 w4 = *(fx4*)&wl[j][q * 4];
      fx4 c4 = *(const fx4*)&cbr[q * 4];
      a += w4 * c4;
    }
    int jg = j0 + j;
    float bias = bih[jg] + (jg < 1024 ? bhh[jg] : 0.f);  // r,z: fold bhh (additive)
    cg[c * G3 + jg] = ((a.x + a.y) + (a.z + a.w)) + bias;
  }
}

// ---------------- f32 -> bf16 convert (proj_w) ----------------
__global__ void k_cvt(const float* __restrict__ src, __hip_bfloat16* __restrict__ dst, int n4) {
  int i = blockIdx.x * blockDim.x + threadIdx.x;
  if (i < n4) {
    fx4 v = *(const fx4*)&src[i * 4];
    sh4 o; o[0] = f2bf(v.x); o[1] = f2bf(v.y); o[2] = f2bf(v.z); o[3] = f2bf(v.w);
    *(sh4*)&dst[i * 4] = o;
  }
}

// ---------------- quantize: argmin + fused vq-loss partial ----------------
__global__ __launch_bounds__(256) void k_quant(const float* __restrict__ feat,
                                               const float* __restrict__ cb,
                                               const double* __restrict__ cn,
                                               int* __restrict__ idxw,
                                               float* __restrict__ outq,
                                               float* __restrict__ outi,
                                               double* __restrict__ lacc) {
  __shared__ float fl[16][516];             // +4 pad: kills 16-way bank conflict
  __shared__ double ss1[16][16], ss2[16][16];
  __shared__ int ii1[16][16], ii2[16][16];
  __shared__ int idxl[16];
  __shared__ float rsv[4];
  int row0 = blockIdx.x * 16;
  int tid = threadIdx.x;
  for (int v = tid; v < 16 * 128; v += 256) {
    int r = v >> 7, q = v & 127;
    *(fx4*)&fl[r][q * 4] = *(const fx4*)&feat[(row0 + r) * D_ + q * 4];
  }
  __syncthreads();
  int r = tid & 15, g = tid >> 4;
  fx4 acc[16];
#pragma unroll
  for (int c = 0; c < 16; ++c) acc[c] = (fx4){0.f, 0.f, 0.f, 0.f};
  for (int ch = 0; ch < 8; ++ch) {          // 8 chunks of 64 dims
    fx4 fc[16];
#pragma unroll
    for (int q = 0; q < 16; ++q) fc[q] = *(fx4*)&fl[r][ch * 64 + q * 4];
#pragma unroll
    for (int c = 0; c < 16; ++c) {
      const float* cbp = &cb[(g * 16 + c) * D_ + ch * 64];
#pragma unroll
      for (int q = 0; q < 16; ++q) {
        fx4 c4 = *(const fx4*)&cbp[q * 4];
        acc[c] += fc[q] * c4;
      }
    }
  }
  double b1 = 1e300, b2 = 1e300; int i1 = 0, i2 = 0;
#pragma unroll
  for (int c = 0; c < 16; ++c) {
    int ci = g * 16 + c;
    double dot = (double)acc[c].x + acc[c].y + acc[c].z + acc[c].w;
    double s = cn[ci] - 2.0 * dot;
    if (s < b1) { b2 = b1; i2 = i1; b1 = s; i1 = ci; }
    else if (s < b2) { b2 = s; i2 = ci; }
  }
  ss1[r][g] = b1; ss2[r][g] = b2; ii1[r][g] = i1; ii2[r][g] = i2;
  __syncthreads();
  if (tid < 16) {
    int rr = tid;
    double c1 = 1e300, c2 = 1e300; int j1 = 0, j2 = 0;
    for (int g2 = 0; g2 < 16; ++g2) {
      double s = ss1[rr][g2]; int ix = ii1[rr][g2];
      if (s < c1 || (s == c1 && ix < j1)) { c2 = c1; j2 = j1; c1 = s; j1 = ix; }
      else if (s < c2 || (s == c2 && ix < j2)) { c2 = s; j2 = ix; }
      s = ss2[rr][g2]; ix = ii2[rr][g2];
      if (s < c1 || (s == c1 && ix < j1)) { c2 = c1; j2 = j1; c1 = s; j1 = ix; }
      else if (s < c2 || (s == c2 && ix < j2)) { c2 = s; j2 = ix; }
    }
    int pick = j1;
    if (c2 - c1 < 1e-4) {                   // near-tie: re-verify both in exact f64
      double d1 = 0.0, d2 = 0.0;
      for (int k = 0; k < D_; ++k) {
        double fv = fl[rr][k];
        d1 += fv * (double)cb[j1 * D_ + k];
        d2 += fv * (double)cb[j2 * D_ + k];
      }
      double e1 = cn[j1] - 2.0 * d1, e2 = cn[j2] - 2.0 * d2;
      if (e2 < e1 || (e2 == e1 && j2 < j1)) pick = j2;
    }
    idxl[rr] = pick;
    idxw[row0 + rr] = pick;
    outi[row0 + rr] = (float)pick;
  }
  __syncthreads();
  float vs = 0.f;
  for (int v = tid; v < 16 * 128; v += 256) {   // gather quantized + vq partial
    int rr = v >> 7, q = v & 127;
    fx4 c4 = *(const fx4*)&cb[idxl[rr] * D_ + q * 4];
    *(fx4*)&outq[(row0 + rr) * D_ + q * 4] = c4;
    fx4 f4 = *(fx4*)&fl[rr][q * 4];
    fx4 d = f4 - c4;
    vs += d.x * d.x + d.y * d.y + d.z * d.z + d.w * d.w;
  }
#pragma unroll
  for (int off = 32; off > 0; off >>= 1) vs += __shfl_down(vs, off);
  if ((tid & 63) == 0) rsv[tid >> 6] = vs;
  __syncthreads();
  if (tid == 0) atomicAdd(&lacc[2], (double)(rsv[0] + rsv[1] + rsv[2] + rsv[3]));
}

// ------- persistent GRU (R2 skeleton) + fused proj GEMM + cp-loss ------------
// grid 64. XCD-derived roles (same-XCD groups by construction). Group g: 8
// batches; block slice s: 64 h-dims (192 W-rows in VGPR) + 64 proj-out dims
// (16 proj_w A-frags in VGPR). Per step: prefetch cg/idx (regs) -> GRU MFMA +
// proj MFMA (reuses h B-frags) -> hg-LDS gate epilogue (512 thr) -> h store to
// hex ping-pong -> sync1 -> publish -> cp epilogue in wait-slack -> poll ->
// sync2. k_proj kernel and the 32MB hid buffer are gone.
__global__ __launch_bounds__(256, 1) void k_gru(const float* __restrict__ whh,
                                                const float* __restrict__ bhh,
                                                const float* __restrict__ cg,
                                                const int* __restrict__ idx,
                                                const __hip_bfloat16* __restrict__ pwb,
                                                const float* __restrict__ pb,
                                                const float* __restrict__ feat,
                                                __hip_bfloat16* __restrict__ hex,
                                                double* __restrict__ lacc,
                                                unsigned int* __restrict__ bar,
                                                unsigned int* __restrict__ coord) {
  int tid = threadIdx.x;
  __shared__ int sh_role, sh_fast;

  // ---- XCD-measured role claim (R7): same-XCD groups guaranteed ----
  if (tid == 0) {
    int xcc = 0;
    asm volatile("s_getreg_b32 %0, hwreg(HW_REG_XCC_ID)" : "=s"(xcc));
    xcc &= 7;
    unsigned slot = __hip_atomic_fetch_add(&coord[xcc], 1u, __ATOMIC_RELAXED,
                                           __HIP_MEMORY_SCOPE_AGENT);
    __hip_atomic_fetch_add(&coord[16], 1u, __ATOMIC_ACQ_REL, __HIP_MEMORY_SCOPE_AGENT);
    while (__hip_atomic_load(&coord[16], __ATOMIC_ACQUIRE, __HIP_MEMORY_SCOPE_AGENT)
           < (unsigned)gridDim.x)
      __builtin_amdgcn_s_sleep(2);
    int role = -1;
    if (slot < 8u) {
      role = xcc * 8 + (int)slot;
    } else {
      for (int x = 0; x < 8 && role < 0; ++x) {
        unsigned cx = __hip_atomic_load(&coord[x], __ATOMIC_RELAXED,
                                        __HIP_MEMORY_SCOPE_AGENT);
        unsigned have = cx < 8u ? cx : 8u;
        if (have < 8u) {
          unsigned s2 = __hip_atomic_fetch_add(&coord[8 + x], 1u, __ATOMIC_RELAXED,
                                               __HIP_MEMORY_SCOPE_AGENT);
          if (s2 < 8u - have) role = x * 8 + (int)(have + s2);
        }
      }
    }
    sh_role = role;
    int fst = 0;
    if (role >= 0) {
      unsigned cgx = __hip_atomic_load(&coord[role >> 3], __ATOMIC_RELAXED,
                                       __HIP_MEMORY_SCOPE_AGENT);
      fst = (cgx >= 8u) ? 1 : 0;
    }
    sh_fast = fst;
    __threadfence();   // one-time L1 hygiene (replay staleness)
  }
  __syncthreads();
  const int role = sh_role;
  if (role < 0) return;
  const bool fast = (sh_fast != 0);
  const int g = role >> 3, s = role & 7;

  int w = tid >> 6, lane = tid & 63, l15 = lane & 15, l4 = lane >> 4;

  // W_hh A-frags (R2 layout): wave w owns local rows [48w, 48w+48)
  sh8 A0[16], A1[16], A2[16];
#pragma unroll
  for (int kt = 0; kt < 16; ++kt) {
#pragma unroll
    for (int t3 = 0; t3 < 3; ++t3) {
      int lr = 48 * w + 16 * t3 + l15;
      int gate = lr >> 6, din = lr & 63;
      const float* wr = &whh[(gate * 512 + s * 64 + din) * D_];
      int k0 = kt * 32 + l4 * 8;
      fx4 x = *(const fx4*)&wr[k0];
      fx4 y = *(const fx4*)&wr[k0 + 4];
      sh8 tt;
      tt[0] = f2bf(x.x); tt[1] = f2bf(x.y); tt[2] = f2bf(x.z); tt[3] = f2bf(x.w);
      tt[4] = f2bf(y.x); tt[5] = f2bf(y.y); tt[6] = f2bf(y.z); tt[7] = f2bf(y.w);
      if (t3 == 0) A0[kt] = tt; else if (t3 == 1) A1[kt] = tt; else A2[kt] = tt;
    }
  }
  // proj_w A-frags: wave w owns proj out-dims s*64 + w*16 .. +15
  sh8 P[16];
#pragma unroll
  for (int kt = 0; kt < 16; ++kt)
    P[kt] = *(const sh8*)&pwb[(size_t)(s * 64 + w * 16 + l15) * D_ + kt * 32 + l4 * 8];

  const bool act = (l15 < 8);
  const int bp = l15 & 7;                    // proj batch col
  const int dgp = s * 64 + w * 16 + l4 * 4;  // proj out-dims (4 per lane)
  fx4 pbv = *(const fx4*)&pb[dgp];

  // gate epilogue constants: this thread's (b0,d) & (b1,d) elements
  const int d = tid & 63, b0 = tid >> 6, b1 = b0 + 4;
  const float bn = bhh[1024 + s * 64 + d];   // n-gate bhh (r,z folded into cg)

  __shared__ float hg[192][9];   // gate pre-activations (pad 9: bank spread)
  __shared__ float hl[8][64];    // f32 h_prev
  for (int i = tid; i < 512; i += 256) ((float*)hl)[i] = 0.f;

  unsigned* const barg = &bar[g * 32];       // one 128B line per group
  float s1 = 0.f, s2 = 0.f;

  for (int t = 0; t < T_; ++t) {
    int cur = t & 1, nxt = cur ^ 1;
    // ---- prefetch (h-independent): idx + 6 gate scalars for the epilogue ----
    int ci0 = idx[(g * 8 + b0) * T_ + t];
    int ci1 = idx[(g * 8 + b1) * T_ + t];
    const float* c0p = &cg[(size_t)ci0 * G3 + s * 64 + d];
    const float* c1p = &cg[(size_t)ci1 * G3 + s * 64 + d];
    float cr0 = c0p[0], cz0 = c0p[512], cn0 = c0p[1024];
    float cr1 = c1p[0], cz1 = c1p[512], cn1 = c1p[1024];

    fx4 a0 = {0, 0, 0, 0}, a1 = {0, 0, 0, 0}, a2 = {0, 0, 0, 0};
    fx4 pacc = {0, 0, 0, 0};
    if (t > 0) {
      const __hip_bfloat16* hb = hex + (size_t)(cur * 8 + g) * 16 * 512;
#pragma unroll
      for (int kt = 0; kt < 16; ++kt) {
        sh8 bfr = *(const sh8*)&hb[l15 * 512 + kt * 32 + l4 * 8];  // rows 8-15 = 0
        a0 = __builtin_amdgcn_mfma_f32_16x16x32_bf16(A0[kt], bfr, a0, 0, 0, 0);
        a1 = __builtin_amdgcn_mfma_f32_16x16x32_bf16(A1[kt], bfr, a1, 0, 0, 0);
        a2 = __builtin_amdgcn_mfma_f32_16x16x32_bf16(A2[kt], bfr, a2, 0, 0, 0);
        pacc = __builtin_amdgcn_mfma_f32_16x16x32_bf16(P[kt], bfr, pacc, 0, 0, 0);
      }
    }
    if (l15 < 8) {
#pragma unroll
      for (int rg = 0; rg < 4; ++rg) {
        hg[48 * w +      l4 * 4 + rg][l15] = a0[rg];
        hg[48 * w + 16 + l4 * 4 + rg][l15] = a1[rg];
        hg[48 * w + 32 + l4 * 4 + rg][l15] = a2[rg];
      }
    }
    __syncthreads();
    // ---- gate epilogue: 512 threads, 1 element each x2, all inputs in regs ----
    {
      float rr = sigm(cr0 + hg[d][b0]);
      float zz = sigm(cz0 + hg[64 + d][b0]);
      float nn = tanh_fast(cn0 + rr * (hg[128 + d][b0] + bn));
      float hv = (1.f - zz) * nn + zz * hl[b0][d];
      hl[b0][d] = hv;
      hex[(size_t)((nxt * 8 + g) * 16 + b0) * 512 + s * 64 + d] = __float2bfloat16(hv);
      rr = sigm(cr1 + hg[d][b1]);
      zz = sigm(cz1 + hg[64 + d][b1]);
      nn = tanh_fast(cn1 + rr * (hg[128 + d][b1] + bn));
      hv = (1.f - zz) * nn + zz * hl[b1][d];
      hl[b1][d] = hv;
      hex[(size_t)((nxt * 8 + g) * 16 + b1) * 512 + s * 64 + d] = __float2bfloat16(hv);
    }
    __syncthreads();   // drains vmcnt(0): h stores visible in (local) L2
    if (tid == 0) {
      if (!fast) __threadfence();
      __hip_atomic_fetch_add(barg, 1u, __ATOMIC_RELEASE, __HIP_MEMORY_SCOPE_AGENT);
    }
    // ---- cp-loss epilogue for step t-1, absorbed into the sync wait ----
    if (t > 0 && act) {
      fx4 f1 = *(const fx4*)&feat[((size_t)(g * 8 + bp) * T_ + t) * D_ + dgp];
      fx4 v = pacc + pbv;
      fx4 d1 = v - f1;
      s1 += d1.x * d1.x + d1.y * d1.y + d1.z * d1.z + d1.w * d1.w;
      if (t < T_ - 1) {
        fx4 f2 = *(const fx4*)&feat[((size_t)(g * 8 + bp) * T_ + t + 1) * D_ + dgp];
        fx4 d2 = v - f2;
        s2 += d2.x * d2.x + d2.y * d2.y + d2.z * d2.z + d2.w * d2.w;
      }
    }
    if (tid == 0) {
      unsigned tgt = 8u * (unsigned)(t + 1);
      while (__hip_atomic_load(barg, __ATOMIC_ACQUIRE, __HIP_MEMORY_SCOPE_AGENT) < tgt)
        __builtin_amdgcn_s_sleep(1);
      if (!fast) __threadfence();
    }
    __syncthreads();
  }

  // ---- cp-loss reduction ----
#pragma unroll
  for (int off = 32; off > 0; off >>= 1) {
    s1 += __shfl_down(s1, off);
    s2 += __shfl_down(s2, off);
  }
  __shared__ float r1[4], r2[4];
  if (lane == 0) { r1[w] = s1; r2[w] = s2; }
  __syncthreads();
  if (tid == 0) {
    atomicAdd(&lacc[0], (double)r1[0] + r1[1] + r1[2] + r1[3]);
    atomicAdd(&lacc[1], (double)r2[0] + r2[1] + r2[2] + r2[3]);
  }
}

// ---------------- finalize losses ----------------
__global__ void k_fin(const double* __restrict__ lacc, float* __restrict__ outl) {
  if (threadIdx.x == 0) {
    double cp = 0.5 * (lacc[0] / ((double)B_ * (T_ - 1) * D_) +
                       lacc[1] / ((double)B_ * (T_ - 2) * D_));
    double vq = 1.25 * lacc[2] / ((double)B_ * T_ * D_);
    outl[0] = (float)(cp + vq);
    outl[1] = (float)cp;
    outl[2] = (float)vq;
  }
}

extern "C" void kernel_launch(void* const* d_in, const int* in_sizes, int n_in,
                              void* d_out, int out_size, void* d_ws, size_t ws_size,
                              hipStream_t stream) {
  (void)in_sizes; (void)n_in; (void)out_size; (void)ws_size;
  const float* feat = (const float*)d_in[0];
  const float* cb   = (const float*)d_in[1];
  const float* wih  = (const float*)d_in[2];
  const float* whh  = (const float*)d_in[3];
  const float* bih  = (const float*)d_in[4];
  const float* bhh  = (const float*)d_in[5];
  const float* pw   = (const float*)d_in[6];
  const float* pb   = (const float*)d_in[7];

  float* out  = (float*)d_out;
  float* outq = out;
  float* outi = out + (size_t)B_ * T_ * D_;
  float* outl = outi + B_ * T_;

  char* ws = (char*)d_ws;
  size_t o = 0;
  auto alloc = [&](size_t sz) { void* p = ws + o; o += (sz + 255) & ~(size_t)255; return p; };
  float*          cg    = (float*)alloc(sizeof(float) * K_ * G3);
  double*         cn    = (double*)alloc(sizeof(double) * K_);
  int*            idxw  = (int*)alloc(sizeof(int) * B_ * T_);
  __hip_bfloat16* pwb   = (__hip_bfloat16*)alloc(sizeof(__hip_bfloat16) * D_ * D_);
  double*         lacc  = (double*)alloc(sizeof(double) * 4);
  unsigned*       bar   = (unsigned*)alloc(sizeof(unsigned) * 8 * 32);
  unsigned*       coord = (unsigned*)alloc(sizeof(unsigned) * 32);
  __hip_bfloat16* hex   = (__hip_bfloat16*)alloc(sizeof(__hip_bfloat16) * 2 * 8 * 16 * 512);

  hipMemsetAsync(lacc,  0, sizeof(double) * 4, stream);
  hipMemsetAsync(bar,   0, sizeof(unsigned) * 8 * 32, stream);
  hipMemsetAsync(coord, 0, sizeof(unsigned) * 32, stream);
  hipMemsetAsync(hex,   0, sizeof(__hip_bfloat16) * 2 * 8 * 16 * 512, stream);

  hipLaunchKernelGGL(k_cnorm, dim3(1), dim3(256), 0, stream, cb, cn);
  hipLaunchKernelGGL(k_cg, dim3(96, 4), dim3(256), 0, stream, cb, wih, bih, bhh, cg);
  hipLaunchKernelGGL(k_cvt, dim3(256), dim3(256), 0, stream, pw, pwb, D_ * D_ / 4);
  hipLaunchKernelGGL(k_quant, dim3(2048), dim3(256), 0, stream, feat, cb, cn, idxw, outq, outi, lacc);
  hipLaunchKernelGGL(k_gru, dim3(64), dim3(256), 0, stream, whh, bhh, cg, idxw, pwb, pb, feat, hex, lacc, bar, coord);
  hipLaunchKernelGGL(k_fin, dim3(1), dim3(64), 0, stream, lacc, outl);
}